// Round 11
// baseline (64.222 us; speedup 1.0000x reference)
//
#include <hip/hip_runtime.h>

#define N_TOT 4096
#define N_HALF 2048
#define DIMS 64
#define BATCH 4
#define TGRID 32             // 4096/128 tile rows
#define PAIRS_PER_BATCH 528  // 32*33/2 triangular 128x128 tiles
#define NWG (BATCH * PAIRS_PER_BATCH)  // 2112, divisible by 8

typedef __attribute__((ext_vector_type(8))) short short8;
typedef __attribute__((ext_vector_type(4))) float f32x4;
typedef __attribute__((ext_vector_type(2))) float f32x2;

#if __has_builtin(__builtin_amdgcn_exp2f)
#define EXP2F(x) __builtin_amdgcn_exp2f(x)
#else
#define EXP2F(x) exp2f(x)
#endif

__device__ __forceinline__ unsigned short f2bf_rne(float f) {
    unsigned int u = __float_as_uint(f);
    unsigned int r = (u + 0x7FFFu + ((u >> 16) & 1u)) >> 16;
    return (unsigned short)r;
}
__device__ __forceinline__ float bf2f(unsigned short h) {
    return __uint_as_float(((unsigned int)h) << 16);
}

// Prep: fp32 -> bf16 hi/lo split, row sq-norms, per-block partials for Ssq and
// colsum. 256 blocks x 256 thr x 16 floats (4 x float4, 1024-float stride).
__global__ __launch_bounds__(256) void prep_kernel(const float* __restrict__ x,
                                                   const float* __restrict__ y,
                                                   unsigned short* __restrict__ hi,
                                                   unsigned short* __restrict__ lo,
                                                   float* __restrict__ sq,
                                                   float* __restrict__ ssq_part,
                                                   float* __restrict__ colsum_part) {
    int g = blockIdx.x;
    int t = threadIdx.x;
    bool isx = g < 128;
    int gg = isx ? g : g - 128;
    int base = gg << 12;             // 4096 floats per block
    int b = gg >> 5;                 // 32 blocks per batch-half
    const float* src = isx ? x : y;

    float q_acc = 0.f;
    float4 c_acc = {0.f, 0.f, 0.f, 0.f};
#pragma unroll
    for (int it = 0; it < 4; ++it) {
        int e = base + (it << 10) + (t << 2);
        int rem = e & 131071;
        float4 v = *(const float4*)(src + e);
        size_t dst = (size_t)b * 262144 + (isx ? 0 : 131072) + rem;
        ushort4 h, l;
        h.x = f2bf_rne(v.x); l.x = f2bf_rne(v.x - bf2f(h.x));
        h.y = f2bf_rne(v.y); l.y = f2bf_rne(v.y - bf2f(h.y));
        h.z = f2bf_rne(v.z); l.z = f2bf_rne(v.z - bf2f(h.z));
        h.w = f2bf_rne(v.w); l.w = f2bf_rne(v.w - bf2f(h.w));
        *(ushort4*)(hi + dst) = h;
        *(ushort4*)(lo + dst) = l;

        // row squared norm: 16 consecutive lanes cover one 64-float row
        float p = fmaf(v.x, v.x, fmaf(v.y, v.y, fmaf(v.z, v.z, v.w * v.w)));
        p += __shfl_xor(p, 1);
        p += __shfl_xor(p, 2);
        p += __shfl_xor(p, 4);
        p += __shfl_xor(p, 8);
        int rwi = rem >> 6;
        if ((t & 15) == 0)
            sq[b * N_TOT + (isx ? rwi : N_HALF + rwi)] = p;

        // wave partial of sum(sq): xor16/xor32 add the wave's 4 distinct rows once
        float q = p;
        q += __shfl_xor(q, 16);
        q += __shfl_xor(q, 32);
        q_acc += q;

        // column partials: lanes t, t^16, t^32, t^48 share the same 4 columns
        float4 c = v;
        c.x += __shfl_xor(c.x, 16); c.y += __shfl_xor(c.y, 16);
        c.z += __shfl_xor(c.z, 16); c.w += __shfl_xor(c.w, 16);
        c.x += __shfl_xor(c.x, 32); c.y += __shfl_xor(c.y, 32);
        c.z += __shfl_xor(c.z, 32); c.w += __shfl_xor(c.w, 32);
        c_acc.x += c.x; c_acc.y += c.y; c_acc.z += c.z; c_acc.w += c.w;
    }

    __shared__ float wsum[4];
    __shared__ float4 csh[4][16];
    int wid = t >> 6;
    if ((t & 63) == 0) wsum[wid] = q_acc;
    if ((t & 63) < 16) csh[wid][t & 63] = c_acc;
    __syncthreads();
    if (t == 0) ssq_part[g] = wsum[0] + wsum[1] + wsum[2] + wsum[3];
    if (t < 16) {
        float4 s0 = csh[0][t], s1 = csh[1][t], s2 = csh[2][t], s3 = csh[3][t];
        float4 o;
        o.x = s0.x + s1.x + s2.x + s3.x;
        o.y = s0.y + s1.y + s2.y + s3.y;
        o.z = s0.z + s1.z + s2.z + s3.z;
        o.w = s0.w + s1.w + s2.w + s3.w;
        *(float4*)(colsum_part + (size_t)g * 64 + t * 4) = o;
    }
}

// Reduce partials -> k0[b]. 4 blocks (one per batch), parallel 16-way sums.
__global__ __launch_bounds__(256) void bw_kernel(const float* __restrict__ ssq_part,
                                                 const float* __restrict__ colsum_part,
                                                 float* __restrict__ k0arr) {
    int b = blockIdx.x;
    int t = threadIdx.x;
    int c = t & 63, q = t >> 6;
    float cs = 0.f;
#pragma unroll
    for (int pp = 0; pp < 16; ++pp) {
        int p = q * 16 + pp;   // 0..63 partial-blocks of this batch
        int g = (p < 32) ? (b * 32 + p) : (128 + b * 32 + (p - 32));
        cs += colsum_part[(size_t)g * 64 + c];
    }
    __shared__ float csq[4][64];
    csq[q][c] = cs;
    __syncthreads();
    if (t < 64) {   // wave 0
        float col = csq[0][t] + csq[1][t] + csq[2][t] + csq[3][t];
        double cc = (double)col * (double)col;
#pragma unroll
        for (int o = 32; o > 0; o >>= 1) cc += __shfl_xor(cc, o);
        int g = (t < 32) ? (b * 32 + t) : (128 + b * 32 + (t - 32));
        double sd = (double)ssq_part[g];
#pragma unroll
        for (int o = 32; o > 0; o >>= 1) sd += __shfl_xor(sd, o);
        if (t == 0) {
            double sumL2 = 2.0 * (double)N_TOT * sd - 2.0 * cc;
            double bw = sumL2 / ((double)N_TOT * (double)N_TOT - (double)N_TOT);
            bw *= 0.25;  // / KERNEL_MUL^(KERNEL_NUM//2)
            k0arr[b] = (float)(-1.4426950408889634 / bw);
        }
    }
}

// Main: triangular 128x128 blocks, 4 waves of 64x64.
// B panel staged once in LDS [slot][row] (r10: cured the r7-r9 spill disease).
// A register-pipelined one row ahead; acc transient per (mf,nf) quadrant.
// NEW (r11): epilogue processes element PAIRS as float2 -> v_pk_fma_f32 /
// v_pk_mul_f32 / v_pk_add_f32 (VOP3P packed fp32), halving epilogue VALU
// instructions (~12 -> ~5.5 per element). exp2 stays scalar (no packed trans).
__global__ __launch_bounds__(256) void mmd_mfma(const unsigned short* __restrict__ hi,
                                                const unsigned short* __restrict__ lo,
                                                const float* __restrict__ sq,
                                                const float* __restrict__ k0arr,
                                                double* __restrict__ pblock) {
    // bijective XCD swizzle (NWG % 8 == 0): r6 cut FETCH 16.7 -> 3.7 MB.
    int wg0 = blockIdx.x;
    int wg = (wg0 & 7) * (NWG / 8) + (wg0 >> 3);
    int b = wg / PAIRS_PER_BATCH;
    int r = wg % PAIRS_PER_BATCH;
    int ib = 0, cum = 0;
    while (r >= cum + (TGRID - ib)) { cum += TGRID - ib; ++ib; }
    int jb = ib + (r - cum);

    int t = threadIdx.x;
    int wid = t >> 6, lane = t & 63;
    int i_base = ib * 128 + (wid >> 1) * 64;
    int j0blk = jb * 128;                 // block's B panel origin
    int j_base = j0blk + (wid & 1) * 64;

    const unsigned short* Hb = hi + (size_t)b * 262144;
    const unsigned short* Lb = lo + (size_t)b * 262144;

    // ---- stage B panel: 128 rows x 64 k, hi+lo, [slot][row] layout ----
    __shared__ short ldsB[16384];   // 32 KB
    {
        int srow = t >> 3;          // 0..31
        int sslot = t & 7;          // 0..7
#pragma unroll
        for (int p = 0; p < 4; ++p) {
            int row = p * 32 + srow;
            size_t gaddr = (size_t)(j0blk + row) * DIMS + sslot * 8;
            short8 vh = *(const short8*)(Hb + gaddr);
            short8 vl = *(const short8*)(Lb + gaddr);
            *(short8*)(ldsB + sslot * 1024 + row * 8) = vh;
            *(short8*)(ldsB + 8192 + sslot * 1024 + row * 8) = vl;
        }
    }
    __syncthreads();

    bool skip = (i_base > j_base);   // strictly-lower wave of a diagonal block
    bool diag = (i_base == j_base);
    float wsign = ((i_base < N_HALF) == (j_base < N_HALF)) ? 1.f : -1.f;

    double acc_d = 0.0;
    if (!skip) {
        float k16 = k0arr[b] * 0.0625f;      // k0/16, wave-uniform
        f32x2 m2 = {-2.f * k16, -2.f * k16};
        const float* sqb = sq + b * N_TOT;
        int lrow = lane & 15;
        int rquad = (lane >> 4) * 4;
        int kbase = (lane >> 4) * 8;
        int jrel = (wid & 1) * 64;           // wave's B rows within panel

        float kj16[4];
#pragma unroll
        for (int nf = 0; nf < 4; ++nf)
            kj16[nf] = k16 * sqb[j_base + nf * 16 + lrow];

        int s0 = (lane >> 4) * 1024;         // k-half 0 slot base (shorts)
        const short* BH = ldsB;
        const short* BL = ldsB + 8192;

        // A row 0 (current) + sq
        size_t ra0 = (size_t)(i_base + lrow) * DIMS + kbase;
        short8 ahc0 = *(const short8*)(Hb + ra0);
        short8 ahc1 = *(const short8*)(Hb + ra0 + 32);
        short8 alc0 = *(const short8*)(Lb + ra0);
        short8 alc1 = *(const short8*)(Lb + ra0 + 32);
        float4 svc = *(const float4*)(sqb + i_base + rquad);

        f32x2 eaccv = {0.f, 0.f};
#pragma unroll
        for (int mf = 0; mf < 4; ++mf) {
            // prefetch next A row from global (hides L2 latency under MFMA)
            short8 ahn0, ahn1, aln0, aln1;
            float4 svn;
            if (mf < 3) {
                size_t ra = (size_t)(i_base + (mf + 1) * 16 + lrow) * DIMS + kbase;
                ahn0 = *(const short8*)(Hb + ra);
                ahn1 = *(const short8*)(Hb + ra + 32);
                aln0 = *(const short8*)(Lb + ra);
                aln1 = *(const short8*)(Lb + ra + 32);
                svn = *(const float4*)(sqb + i_base + (mf + 1) * 16 + rquad);
            }

            // ki pairs for packed epilogue
            f32x2 kis[2];
            kis[0] = (f32x2){k16 * svc.x, k16 * svc.y};
            kis[1] = (f32x2){k16 * svc.z, k16 * svc.w};
#pragma unroll
            for (int nf = 0; nf < 4; ++nf) {
                int rr = (jrel + nf * 16 + lrow) * 8;
                short8 bh0 = *(const short8*)(BH + s0 + rr);
                short8 bh1 = *(const short8*)(BH + s0 + 4096 + rr);
                short8 bl0 = *(const short8*)(BL + s0 + rr);
                short8 bl1 = *(const short8*)(BL + s0 + 4096 + rr);

                // two independent 3-deep chains (one per k-half)
                f32x4 accP = (f32x4){0.f, 0.f, 0.f, 0.f};
                f32x4 accQ = (f32x4){0.f, 0.f, 0.f, 0.f};
                accP = __builtin_amdgcn_mfma_f32_16x16x32_bf16(ahc0, bh0, accP, 0, 0, 0);
                accQ = __builtin_amdgcn_mfma_f32_16x16x32_bf16(ahc1, bh1, accQ, 0, 0, 0);
                accP = __builtin_amdgcn_mfma_f32_16x16x32_bf16(ahc0, bl0, accP, 0, 0, 0);
                accQ = __builtin_amdgcn_mfma_f32_16x16x32_bf16(ahc1, bl1, accQ, 0, 0, 0);
                accP = __builtin_amdgcn_mfma_f32_16x16x32_bf16(alc0, bh0, accP, 0, 0, 0);
                accQ = __builtin_amdgcn_mfma_f32_16x16x32_bf16(alc1, bh1, accQ, 0, 0, 0);

                f32x2 kj2 = {kj16[nf], kj16[nf]};
#pragma unroll
                for (int h = 0; h < 2; ++h) {
                    f32x2 aP = {accP[2 * h], accP[2 * h + 1]};
                    f32x2 aQ = {accQ[2 * h], accQ[2 * h + 1]};
                    f32x2 sk = kis[h] + kj2;                  // pk_add
                    f32x2 tt = m2 * aQ + (m2 * aP + sk);      // 2x pk_fma
                    f32x2 e4;
                    e4.x = EXP2F(tt.x);
                    e4.y = EXP2F(tt.y);
                    f32x2 e3 = e4 * e4;                       // pk_mul chain
                    f32x2 e2 = e3 * e3;
                    f32x2 e1 = e2 * e2;
                    f32x2 e0 = e1 * e1;
                    f32x2 es = (e0 + e1) + (e2 + e3);         // pk_adds
                    es = es + e4;
                    if (diag) {
                        int i0r = mf * 16 + rquad + 2 * h;    // relative rows
                        int j = nf * 16 + lrow;
                        float w0 = (j > i0r) ? 2.f : ((j == i0r) ? 1.f : 0.f);
                        float w1 = (j > i0r + 1) ? 2.f : ((j == i0r + 1) ? 1.f : 0.f);
                        es.x *= w0;
                        es.y *= w1;
                    }
                    eaccv += es;                               // pk_add
                }
            }

            if (mf < 3) {
                ahc0 = ahn0; ahc1 = ahn1;
                alc0 = aln0; alc1 = aln1;
                svc = svn;
            }
        }
        float eacc = eaccv.x + eaccv.y;
        acc_d = (double)(eacc * (diag ? wsign : 2.f * wsign));
    }

#pragma unroll
    for (int o = 32; o > 0; o >>= 1) acc_d += __shfl_down(acc_d, o);
    __shared__ double wred[4];
    if ((t & 63) == 0) wred[wid] = acc_d;
    __syncthreads();
    if (t == 0)
        pblock[wg] = wred[0] + wred[1] + wred[2] + wred[3];
}

// Final reduce: block b sums its batch's 528 block partials.
__global__ __launch_bounds__(256) void finalize_kernel(const double* __restrict__ pblock,
                                                       float* __restrict__ out) {
    int b = blockIdx.x, t = threadIdx.x;
    const double* p = pblock + (size_t)b * PAIRS_PER_BATCH;
    double s = 0.0;
    for (int i = t; i < PAIRS_PER_BATCH; i += 256) s += p[i];
#pragma unroll
    for (int o = 32; o > 0; o >>= 1) s += __shfl_down(s, o);
    __shared__ double w[4];
    if ((t & 63) == 0) w[t >> 6] = s;
    __syncthreads();
    if (t == 0)
        out[b] = (float)((w[0] + w[1] + w[2] + w[3]) / ((double)N_HALF * (double)N_HALF));
}

extern "C" void kernel_launch(void* const* d_in, const int* in_sizes, int n_in,
                              void* d_out, int out_size, void* d_ws, size_t ws_size,
                              hipStream_t stream) {
    const float* x = (const float*)d_in[0];
    const float* y = (const float*)d_in[1];
    float* out = (float*)d_out;
    char* ws = (char*)d_ws;

    double* pblock      = (double*)ws;                    // 2112*8 = 16896 B
    float*  k0arr       = (float*)(ws + 16896);           // 16 B
    float*  ssq_part    = (float*)(ws + 20480);           // 1 KB
    float*  colsum_part = (float*)(ws + 24576);           // 64 KB
    float*  sq          = (float*)(ws + 98304);           // 64 KB
    unsigned short* tot_hi = (unsigned short*)(ws + 163840);            // 2 MB
    unsigned short* tot_lo = (unsigned short*)(ws + 163840 + 2097152);  // 2 MB

    // no memset needed: every ws word consumed is unconditionally written
    // earlier in the same call (no atomic accumulators).

    prep_kernel<<<256, 256, 0, stream>>>(x, y, tot_hi, tot_lo, sq, ssq_part, colsum_part);
    bw_kernel<<<BATCH, 256, 0, stream>>>(ssq_part, colsum_part, k0arr);
    mmd_mfma<<<NWG, 256, 0, stream>>>(tot_hi, tot_lo, sq, k0arr, pblock);
    finalize_kernel<<<BATCH, 256, 0, stream>>>(pblock, out);
}

// Round 12
// 49.848 us; speedup vs baseline: 1.2884x; 1.2884x over previous
//
#include <hip/hip_runtime.h>

#define N_TOT 4096
#define N_HALF 2048
#define DIMS 64
#define BATCH 4
#define TGRID 32             // 4096/128 tile rows
#define PAIRS_PER_BATCH 528  // 32*33/2 triangular 128x128 tiles
#define NWG (BATCH * PAIRS_PER_BATCH)  // 2112, divisible by 8

typedef __attribute__((ext_vector_type(8))) short short8;
typedef __attribute__((ext_vector_type(4))) float f32x4;

#if __has_builtin(__builtin_amdgcn_exp2f)
#define EXP2F(x) __builtin_amdgcn_exp2f(x)
#else
#define EXP2F(x) exp2f(x)
#endif

__device__ __forceinline__ unsigned short f2bf_rne(float f) {
    unsigned int u = __float_as_uint(f);
    unsigned int r = (u + 0x7FFFu + ((u >> 16) & 1u)) >> 16;
    return (unsigned short)r;
}
__device__ __forceinline__ float bf2f(unsigned short h) {
    return __uint_as_float(((unsigned int)h) << 16);
}

// Prep: fp32 -> bf16 hi/lo split, row sq-norms, per-block partials for Ssq and
// colsum. 256 blocks x 256 thr x 16 floats (4 x float4, 1024-float stride).
__global__ __launch_bounds__(256) void prep_kernel(const float* __restrict__ x,
                                                   const float* __restrict__ y,
                                                   unsigned short* __restrict__ hi,
                                                   unsigned short* __restrict__ lo,
                                                   float* __restrict__ sq,
                                                   float* __restrict__ ssq_part,
                                                   float* __restrict__ colsum_part) {
    int g = blockIdx.x;
    int t = threadIdx.x;
    bool isx = g < 128;
    int gg = isx ? g : g - 128;
    int base = gg << 12;             // 4096 floats per block
    int b = gg >> 5;                 // 32 blocks per batch-half
    const float* src = isx ? x : y;

    float q_acc = 0.f;
    float4 c_acc = {0.f, 0.f, 0.f, 0.f};
#pragma unroll
    for (int it = 0; it < 4; ++it) {
        int e = base + (it << 10) + (t << 2);
        int rem = e & 131071;
        float4 v = *(const float4*)(src + e);
        size_t dst = (size_t)b * 262144 + (isx ? 0 : 131072) + rem;
        ushort4 h, l;
        h.x = f2bf_rne(v.x); l.x = f2bf_rne(v.x - bf2f(h.x));
        h.y = f2bf_rne(v.y); l.y = f2bf_rne(v.y - bf2f(h.y));
        h.z = f2bf_rne(v.z); l.z = f2bf_rne(v.z - bf2f(h.z));
        h.w = f2bf_rne(v.w); l.w = f2bf_rne(v.w - bf2f(h.w));
        *(ushort4*)(hi + dst) = h;
        *(ushort4*)(lo + dst) = l;

        // row squared norm: 16 consecutive lanes cover one 64-float row
        float p = fmaf(v.x, v.x, fmaf(v.y, v.y, fmaf(v.z, v.z, v.w * v.w)));
        p += __shfl_xor(p, 1);
        p += __shfl_xor(p, 2);
        p += __shfl_xor(p, 4);
        p += __shfl_xor(p, 8);
        int rwi = rem >> 6;
        if ((t & 15) == 0)
            sq[b * N_TOT + (isx ? rwi : N_HALF + rwi)] = p;

        // wave partial of sum(sq): xor16/xor32 add the wave's 4 distinct rows once
        float q = p;
        q += __shfl_xor(q, 16);
        q += __shfl_xor(q, 32);
        q_acc += q;

        // column partials: lanes t, t^16, t^32, t^48 share the same 4 columns
        float4 c = v;
        c.x += __shfl_xor(c.x, 16); c.y += __shfl_xor(c.y, 16);
        c.z += __shfl_xor(c.z, 16); c.w += __shfl_xor(c.w, 16);
        c.x += __shfl_xor(c.x, 32); c.y += __shfl_xor(c.y, 32);
        c.z += __shfl_xor(c.z, 32); c.w += __shfl_xor(c.w, 32);
        c_acc.x += c.x; c_acc.y += c.y; c_acc.z += c.z; c_acc.w += c.w;
    }

    __shared__ float wsum[4];
    __shared__ float4 csh[4][16];
    int wid = t >> 6;
    if ((t & 63) == 0) wsum[wid] = q_acc;
    if ((t & 63) < 16) csh[wid][t & 63] = c_acc;
    __syncthreads();
    if (t == 0) ssq_part[g] = wsum[0] + wsum[1] + wsum[2] + wsum[3];
    if (t < 16) {
        float4 s0 = csh[0][t], s1 = csh[1][t], s2 = csh[2][t], s3 = csh[3][t];
        float4 o;
        o.x = s0.x + s1.x + s2.x + s3.x;
        o.y = s0.y + s1.y + s2.y + s3.y;
        o.z = s0.z + s1.z + s2.z + s3.z;
        o.w = s0.w + s1.w + s2.w + s3.w;
        *(float4*)(colsum_part + (size_t)g * 64 + t * 4) = o;
    }
}

// Reduce partials -> k0[b]. 4 blocks (one per batch), parallel 16-way sums.
__global__ __launch_bounds__(256) void bw_kernel(const float* __restrict__ ssq_part,
                                                 const float* __restrict__ colsum_part,
                                                 float* __restrict__ k0arr) {
    int b = blockIdx.x;
    int t = threadIdx.x;
    int c = t & 63, q = t >> 6;
    float cs = 0.f;
#pragma unroll
    for (int pp = 0; pp < 16; ++pp) {
        int p = q * 16 + pp;   // 0..63 partial-blocks of this batch
        int g = (p < 32) ? (b * 32 + p) : (128 + b * 32 + (p - 32));
        cs += colsum_part[(size_t)g * 64 + c];
    }
    __shared__ float csq[4][64];
    csq[q][c] = cs;
    __syncthreads();
    if (t < 64) {   // wave 0
        float col = csq[0][t] + csq[1][t] + csq[2][t] + csq[3][t];
        double cc = (double)col * (double)col;
#pragma unroll
        for (int o = 32; o > 0; o >>= 1) cc += __shfl_xor(cc, o);
        int g = (t < 32) ? (b * 32 + t) : (128 + b * 32 + (t - 32));
        double sd = (double)ssq_part[g];
#pragma unroll
        for (int o = 32; o > 0; o >>= 1) sd += __shfl_xor(sd, o);
        if (t == 0) {
            double sumL2 = 2.0 * (double)N_TOT * sd - 2.0 * cc;
            double bw = sumL2 / ((double)N_TOT * (double)N_TOT - (double)N_TOT);
            bw *= 0.25;  // / KERNEL_MUL^(KERNEL_NUM//2)
            k0arr[b] = (float)(-1.4426950408889634 / bw);
        }
    }
}

// Main: triangular 128x128 blocks, 4 waves of 64x64. (r10 structure, reverted
// from r11's packed-f32x2 epilogue: that raised VGPR to 132, occupancy 9%.)
// B panel staged once in LDS [slot][row]; A register-pipelined one row ahead;
// acc transient per (mf,nf) quadrant; scalar squaring-chain epilogue.
// NEW (r12): async-STAGE split — staging global loads -> issue this wave's
// A-row-0/kj/sq prologue loads -> LDS writes -> barrier, so the prologue's
// L2 latency hides under staging latency + barrier wait (G15).
__global__ __launch_bounds__(256) void mmd_mfma(const unsigned short* __restrict__ hi,
                                                const unsigned short* __restrict__ lo,
                                                const float* __restrict__ sq,
                                                const float* __restrict__ k0arr,
                                                double* __restrict__ pblock) {
    // bijective XCD swizzle (NWG % 8 == 0): r6 cut FETCH 16.7 -> 3.7 MB.
    int wg0 = blockIdx.x;
    int wg = (wg0 & 7) * (NWG / 8) + (wg0 >> 3);
    int b = wg / PAIRS_PER_BATCH;
    int r = wg % PAIRS_PER_BATCH;
    int ib = 0, cum = 0;
    while (r >= cum + (TGRID - ib)) { cum += TGRID - ib; ++ib; }
    int jb = ib + (r - cum);

    int t = threadIdx.x;
    int wid = t >> 6, lane = t & 63;
    int i_base = ib * 128 + (wid >> 1) * 64;
    int j0blk = jb * 128;                 // block's B panel origin
    int j_base = j0blk + (wid & 1) * 64;

    const unsigned short* Hb = hi + (size_t)b * 262144;
    const unsigned short* Lb = lo + (size_t)b * 262144;

    bool skip = (i_base > j_base);   // strictly-lower wave of a diagonal block
    bool diag = (i_base == j_base);
    float wsign = ((i_base < N_HALF) == (j_base < N_HALF)) ? 1.f : -1.f;

    const float* sqb = sq + b * N_TOT;
    int lrow = lane & 15;
    int rquad = (lane >> 4) * 4;
    int kbase = (lane >> 4) * 8;

    __shared__ short ldsB[16384];   // 32 KB: BH [0,8192) BL [8192,16384) shorts
    int srow = t >> 3;          // 0..31
    int sslot = t & 7;          // 0..7

    // ---- phase 1: issue staging loads into registers ----
    short8 vh0, vh1, vh2, vh3, vl0, vl1, vl2, vl3;
    {
        size_t g0 = (size_t)(j0blk + srow) * DIMS + sslot * 8;
        size_t g1 = (size_t)(j0blk + 32 + srow) * DIMS + sslot * 8;
        size_t g2 = (size_t)(j0blk + 64 + srow) * DIMS + sslot * 8;
        size_t g3 = (size_t)(j0blk + 96 + srow) * DIMS + sslot * 8;
        vh0 = *(const short8*)(Hb + g0); vl0 = *(const short8*)(Lb + g0);
        vh1 = *(const short8*)(Hb + g1); vl1 = *(const short8*)(Lb + g1);
        vh2 = *(const short8*)(Hb + g2); vl2 = *(const short8*)(Lb + g2);
        vh3 = *(const short8*)(Hb + g3); vl3 = *(const short8*)(Lb + g3);
    }

    // ---- phase 2: issue this wave's prologue loads (latency hides under
    //      staging latency + barrier) ----
    float kj16[4];
    short8 ahc0, ahc1, alc0, alc1;
    float4 svc;
    float k16 = 0.f;
    if (!skip) {
        k16 = k0arr[b] * 0.0625f;        // k0/16, wave-uniform
#pragma unroll
        for (int nf = 0; nf < 4; ++nf)
            kj16[nf] = k16 * sqb[j_base + nf * 16 + lrow];
        size_t ra0 = (size_t)(i_base + lrow) * DIMS + kbase;
        ahc0 = *(const short8*)(Hb + ra0);
        ahc1 = *(const short8*)(Hb + ra0 + 32);
        alc0 = *(const short8*)(Lb + ra0);
        alc1 = *(const short8*)(Lb + ra0 + 32);
        svc = *(const float4*)(sqb + i_base + rquad);
    }

    // ---- phase 3: write staged B to LDS, barrier ----
    {
        int o = sslot * 1024 + srow * 8;
        *(short8*)(ldsB + o)              = vh0;
        *(short8*)(ldsB + o + 256)        = vh1;   // (32 rows)*8
        *(short8*)(ldsB + o + 512)        = vh2;
        *(short8*)(ldsB + o + 768)        = vh3;
        *(short8*)(ldsB + 8192 + o)       = vl0;
        *(short8*)(ldsB + 8192 + o + 256) = vl1;
        *(short8*)(ldsB + 8192 + o + 512) = vl2;
        *(short8*)(ldsB + 8192 + o + 768) = vl3;
    }
    __syncthreads();

    double acc_d = 0.0;
    if (!skip) {
        float m2k16 = -2.f * k16;
        int jrel = (wid & 1) * 64;           // wave's B rows within panel
        int s0 = (lane >> 4) * 1024;         // k-half 0 slot base (shorts)
        const short* BH = ldsB;
        const short* BL = ldsB + 8192;

        float eacc0 = 0.f, eacc1 = 0.f;
#pragma unroll
        for (int mf = 0; mf < 4; ++mf) {
            // prefetch next A row from global (hides L2 latency under MFMA)
            short8 ahn0, ahn1, aln0, aln1;
            float4 svn;
            if (mf < 3) {
                size_t ra = (size_t)(i_base + (mf + 1) * 16 + lrow) * DIMS + kbase;
                ahn0 = *(const short8*)(Hb + ra);
                ahn1 = *(const short8*)(Hb + ra + 32);
                aln0 = *(const short8*)(Lb + ra);
                aln1 = *(const short8*)(Lb + ra + 32);
                svn = *(const float4*)(sqb + i_base + (mf + 1) * 16 + rquad);
            }

            float ki[4] = {k16 * svc.x, k16 * svc.y, k16 * svc.z, k16 * svc.w};
#pragma unroll
            for (int nf = 0; nf < 4; ++nf) {
                int rr = (jrel + nf * 16 + lrow) * 8;
                short8 bh0 = *(const short8*)(BH + s0 + rr);
                short8 bh1 = *(const short8*)(BH + s0 + 4096 + rr);
                short8 bl0 = *(const short8*)(BL + s0 + rr);
                short8 bl1 = *(const short8*)(BL + s0 + 4096 + rr);

                // two independent 3-deep chains (one per k-half)
                f32x4 accP = (f32x4){0.f, 0.f, 0.f, 0.f};
                f32x4 accQ = (f32x4){0.f, 0.f, 0.f, 0.f};
                accP = __builtin_amdgcn_mfma_f32_16x16x32_bf16(ahc0, bh0, accP, 0, 0, 0);
                accQ = __builtin_amdgcn_mfma_f32_16x16x32_bf16(ahc1, bh1, accQ, 0, 0, 0);
                accP = __builtin_amdgcn_mfma_f32_16x16x32_bf16(ahc0, bl0, accP, 0, 0, 0);
                accQ = __builtin_amdgcn_mfma_f32_16x16x32_bf16(ahc1, bl1, accQ, 0, 0, 0);
                accP = __builtin_amdgcn_mfma_f32_16x16x32_bf16(alc0, bh0, accP, 0, 0, 0);
                accQ = __builtin_amdgcn_mfma_f32_16x16x32_bf16(alc1, bh1, accQ, 0, 0, 0);

#pragma unroll
                for (int rg = 0; rg < 4; ++rg) {
                    float t16 = fmaf(m2k16, accQ[rg],
                                     fmaf(m2k16, accP[rg], ki[rg] + kj16[nf]));
                    float e4 = EXP2F(t16);       // exp2(t/16)
                    float e3 = e4 * e4;          // squaring chain (full-rate muls)
                    float e2 = e3 * e3;
                    float e1 = e2 * e2;
                    float e0 = e1 * e1;
                    float es = ((e0 + e1) + (e2 + e3)) + e4;
                    if (diag) {
                        int i = mf * 16 + rquad + rg;   // relative, i_base==j_base
                        int j = nf * 16 + lrow;
                        float w = (j > i) ? 2.f : ((j == i) ? 1.f : 0.f);
                        es *= w;
                    }
                    if (rg & 1) eacc1 += es; else eacc0 += es;
                }
            }

            if (mf < 3) {
                ahc0 = ahn0; ahc1 = ahn1;
                alc0 = aln0; alc1 = aln1;
                svc = svn;
            }
        }
        float eacc = eacc0 + eacc1;
        acc_d = (double)(eacc * (diag ? wsign : 2.f * wsign));
    }

#pragma unroll
    for (int o = 32; o > 0; o >>= 1) acc_d += __shfl_down(acc_d, o);
    __shared__ double wred[4];
    if ((t & 63) == 0) wred[wid] = acc_d;
    __syncthreads();
    if (t == 0)
        pblock[wg] = wred[0] + wred[1] + wred[2] + wred[3];
}

// Final reduce: block b sums its batch's 528 block partials.
__global__ __launch_bounds__(256) void finalize_kernel(const double* __restrict__ pblock,
                                                       float* __restrict__ out) {
    int b = blockIdx.x, t = threadIdx.x;
    const double* p = pblock + (size_t)b * PAIRS_PER_BATCH;
    double s = 0.0;
    for (int i = t; i < PAIRS_PER_BATCH; i += 256) s += p[i];
#pragma unroll
    for (int o = 32; o > 0; o >>= 1) s += __shfl_down(s, o);
    __shared__ double w[4];
    if ((t & 63) == 0) w[t >> 6] = s;
    __syncthreads();
    if (t == 0)
        out[b] = (float)((w[0] + w[1] + w[2] + w[3]) / ((double)N_HALF * (double)N_HALF));
}

extern "C" void kernel_launch(void* const* d_in, const int* in_sizes, int n_in,
                              void* d_out, int out_size, void* d_ws, size_t ws_size,
                              hipStream_t stream) {
    const float* x = (const float*)d_in[0];
    const float* y = (const float*)d_in[1];
    float* out = (float*)d_out;
    char* ws = (char*)d_ws;

    double* pblock      = (double*)ws;                    // 2112*8 = 16896 B
    float*  k0arr       = (float*)(ws + 16896);           // 16 B
    float*  ssq_part    = (float*)(ws + 20480);           // 1 KB
    float*  colsum_part = (float*)(ws + 24576);           // 64 KB
    float*  sq          = (float*)(ws + 98304);           // 64 KB
    unsigned short* tot_hi = (unsigned short*)(ws + 163840);            // 2 MB
    unsigned short* tot_lo = (unsigned short*)(ws + 163840 + 2097152);  // 2 MB

    // no memset needed: every ws word consumed is unconditionally written
    // earlier in the same call (no atomic accumulators).

    prep_kernel<<<256, 256, 0, stream>>>(x, y, tot_hi, tot_lo, sq, ssq_part, colsum_part);
    bw_kernel<<<BATCH, 256, 0, stream>>>(ssq_part, colsum_part, k0arr);
    mmd_mfma<<<NWG, 256, 0, stream>>>(tot_hi, tot_lo, sq, k0arr, pblock);
    finalize_kernel<<<BATCH, 256, 0, stream>>>(pblock, out);
}

// Round 13
// 43.888 us; speedup vs baseline: 1.4633x; 1.1358x over previous
//
#include <hip/hip_runtime.h>

#define N_TOT 4096
#define N_HALF 2048
#define DIMS 64
#define BATCH 4
#define WGRID 64              // 4096/64 wave-tile rows
#define TRI_PER_BATCH 2080    // 64*65/2 upper-tri 64x64 wave-tiles
#define NWG (BATCH * TRI_PER_BATCH)   // 8320, divisible by 8

typedef __attribute__((ext_vector_type(8))) short short8;
typedef __attribute__((ext_vector_type(4))) float f32x4;

#if __has_builtin(__builtin_amdgcn_exp2f)
#define EXP2F(x) __builtin_amdgcn_exp2f(x)
#else
#define EXP2F(x) exp2f(x)
#endif

__device__ __forceinline__ unsigned short f2bf_rne(float f) {
    unsigned int u = __float_as_uint(f);
    unsigned int r = (u + 0x7FFFu + ((u >> 16) & 1u)) >> 16;
    return (unsigned short)r;
}
__device__ __forceinline__ float bf2f(unsigned short h) {
    return __uint_as_float(((unsigned int)h) << 16);
}

// Prep: fp32 -> bf16 hi/lo split, row sq-norms, per-block partials for Ssq and
// colsum. 256 blocks x 256 thr x 16 floats.
__global__ __launch_bounds__(256) void prep_kernel(const float* __restrict__ x,
                                                   const float* __restrict__ y,
                                                   unsigned short* __restrict__ hi,
                                                   unsigned short* __restrict__ lo,
                                                   float* __restrict__ sq,
                                                   float* __restrict__ ssq_part,
                                                   float* __restrict__ colsum_part) {
    int g = blockIdx.x;
    int t = threadIdx.x;
    bool isx = g < 128;
    int gg = isx ? g : g - 128;
    int base = gg << 12;
    int b = gg >> 5;
    const float* src = isx ? x : y;

    float q_acc = 0.f;
    float4 c_acc = {0.f, 0.f, 0.f, 0.f};
#pragma unroll
    for (int it = 0; it < 4; ++it) {
        int e = base + (it << 10) + (t << 2);
        int rem = e & 131071;
        float4 v = *(const float4*)(src + e);
        unsigned dst = (unsigned)b * 262144u + (isx ? 0u : 131072u) + (unsigned)rem;
        ushort4 h, l;
        h.x = f2bf_rne(v.x); l.x = f2bf_rne(v.x - bf2f(h.x));
        h.y = f2bf_rne(v.y); l.y = f2bf_rne(v.y - bf2f(h.y));
        h.z = f2bf_rne(v.z); l.z = f2bf_rne(v.z - bf2f(h.z));
        h.w = f2bf_rne(v.w); l.w = f2bf_rne(v.w - bf2f(h.w));
        *(ushort4*)(hi + dst) = h;
        *(ushort4*)(lo + dst) = l;

        float p = fmaf(v.x, v.x, fmaf(v.y, v.y, fmaf(v.z, v.z, v.w * v.w)));
        p += __shfl_xor(p, 1);
        p += __shfl_xor(p, 2);
        p += __shfl_xor(p, 4);
        p += __shfl_xor(p, 8);
        int rwi = rem >> 6;
        if ((t & 15) == 0)
            sq[b * N_TOT + (isx ? rwi : N_HALF + rwi)] = p;

        float q = p;
        q += __shfl_xor(q, 16);
        q += __shfl_xor(q, 32);
        q_acc += q;

        float4 c = v;
        c.x += __shfl_xor(c.x, 16); c.y += __shfl_xor(c.y, 16);
        c.z += __shfl_xor(c.z, 16); c.w += __shfl_xor(c.w, 16);
        c.x += __shfl_xor(c.x, 32); c.y += __shfl_xor(c.y, 32);
        c.z += __shfl_xor(c.z, 32); c.w += __shfl_xor(c.w, 32);
        c_acc.x += c.x; c_acc.y += c.y; c_acc.z += c.z; c_acc.w += c.w;
    }

    __shared__ float wsum[4];
    __shared__ float4 csh[4][16];
    int wid = t >> 6;
    if ((t & 63) == 0) wsum[wid] = q_acc;
    if ((t & 63) < 16) csh[wid][t & 63] = c_acc;
    __syncthreads();
    if (t == 0) ssq_part[g] = wsum[0] + wsum[1] + wsum[2] + wsum[3];
    if (t < 16) {
        float4 s0 = csh[0][t], s1 = csh[1][t], s2 = csh[2][t], s3 = csh[3][t];
        float4 o;
        o.x = s0.x + s1.x + s2.x + s3.x;
        o.y = s0.y + s1.y + s2.y + s3.y;
        o.z = s0.z + s1.z + s2.z + s3.z;
        o.w = s0.w + s1.w + s2.w + s3.w;
        *(float4*)(colsum_part + (size_t)g * 64 + t * 4) = o;
    }
}

// Reduce partials -> k0[b]. 4 blocks (one per batch).
__global__ __launch_bounds__(256) void bw_kernel(const float* __restrict__ ssq_part,
                                                 const float* __restrict__ colsum_part,
                                                 float* __restrict__ k0arr) {
    int b = blockIdx.x;
    int t = threadIdx.x;
    int c = t & 63, q = t >> 6;
    float cs = 0.f;
#pragma unroll
    for (int pp = 0; pp < 16; ++pp) {
        int p = q * 16 + pp;
        int g = (p < 32) ? (b * 32 + p) : (128 + b * 32 + (p - 32));
        cs += colsum_part[(size_t)g * 64 + c];
    }
    __shared__ float csq[4][64];
    csq[q][c] = cs;
    __syncthreads();
    if (t < 64) {
        float col = csq[0][t] + csq[1][t] + csq[2][t] + csq[3][t];
        double cc = (double)col * (double)col;
#pragma unroll
        for (int o = 32; o > 0; o >>= 1) cc += __shfl_xor(cc, o);
        int g = (t < 32) ? (b * 32 + t) : (128 + b * 32 + (t - 32));
        double sd = (double)ssq_part[g];
#pragma unroll
        for (int o = 32; o > 0; o >>= 1) sd += __shfl_xor(sd, o);
        if (t == 0) {
            double sumL2 = 2.0 * (double)N_TOT * sd - 2.0 * cc;
            double bw = sumL2 / ((double)N_TOT * (double)N_TOT - (double)N_TOT);
            bw *= 0.25;
            k0arr[b] = (float)(-1.4426950408889634 / bw);
        }
    }
}

// Main: SINGLE-WAVE blocks (64 threads), 64x64 upper-tri wave-tiles, NO
// barriers anywhere. 2-pass MFMA: dot' = (ah+al)*bh = a*bh exactly -> B-lo
// never needed (MFMA -33%, LDS panel 8 KB, LDS reads halve). B-hi staged
// wave-locally; A hi+lo direct from L2 (consecutive tiles share A rows).
__global__ void mmd_mfma(const unsigned short* __restrict__ hi,
                         const unsigned short* __restrict__ lo,
                         const float* __restrict__ sq,
                         const float* __restrict__ k0arr,
                         double* __restrict__ pblock) {
    // bijective XCD swizzle (NWG % 8 == 0)
    int wg0 = blockIdx.x;
    int wg = (wg0 & 7) * (NWG / 8) + (wg0 >> 3);
    int b = wg / TRI_PER_BATCH;
    int r = wg % TRI_PER_BATCH;
    int ib = 0, cum = 0;
    while (r >= cum + (WGRID - ib)) { cum += WGRID - ib; ++ib; }
    int jb = ib + (r - cum);
    unsigned i0 = (unsigned)ib * 64u;
    unsigned j0 = (unsigned)jb * 64u;
    int lane = threadIdx.x;           // 0..63

    const unsigned short* Hb = hi + (unsigned)b * 262144u;
    const unsigned short* Lb = lo + (unsigned)b * 262144u;
    const float* sqb = sq + b * N_TOT;

    // ---- stage B-hi panel (64 rows x 64 k = 8 KB), [slot8][row64] layout ----
    // shorts index = slot*512 + row*8; slot s holds k-chunk s (8 bf16).
    __shared__ short ldsB[4096];
    {
        unsigned gb = (j0 + (unsigned)lane) * 64u;
#pragma unroll
        for (int k = 0; k < 8; ++k) {
            short8 v = *(const short8*)(Hb + gb + (unsigned)k * 8u);
            *(short8*)(ldsB + k * 512 + lane * 8) = v;
        }
    }
    // no __syncthreads: single wave; compiler orders ds_read after ds_write.

    bool diag = (ib == jb);
    float wsign = ((i0 < (unsigned)N_HALF) == (j0 < (unsigned)N_HALF)) ? 1.f : -1.f;
    float k16 = k0arr[b] * 0.0625f;      // k0/16
    float m2k16 = -2.f * k16;
    unsigned lrow = (unsigned)(lane & 15);
    unsigned grp = (unsigned)(lane >> 4);   // k-chunk group 0..3
    unsigned rquad = grp * 4u;
    unsigned kbase = grp * 8u;

    float kj16[4];
#pragma unroll
    for (int nf = 0; nf < 4; ++nf)
        kj16[nf] = k16 * sqb[j0 + (unsigned)nf * 16u + lrow];

    const short* B0 = ldsB + grp * 512;          // k-half 0 slot base
    float eacc0 = 0.f, eacc1 = 0.f;

#pragma unroll
    for (int mf = 0; mf < 4; ++mf) {
        unsigned ra = (i0 + (unsigned)mf * 16u + lrow) * 64u + kbase;
        short8 ah0 = *(const short8*)(Hb + ra);
        short8 ah1 = *(const short8*)(Hb + ra + 32u);
        short8 al0 = *(const short8*)(Lb + ra);
        short8 al1 = *(const short8*)(Lb + ra + 32u);
        float4 sv = *(const float4*)(sqb + i0 + (unsigned)mf * 16u + rquad);
        float ki[4] = {k16 * sv.x, k16 * sv.y, k16 * sv.z, k16 * sv.w};

#pragma unroll
        for (int nf = 0; nf < 4; ++nf) {
            const short* bp = B0 + (nf * 16 + (int)lrow) * 8;
            short8 bh0 = *(const short8*)(bp);
            short8 bh1 = *(const short8*)(bp + 2048);   // k-half 1 (slot+4)

            // dot = a*bh exactly: (ah + al) x bh via two passes per k-half
            f32x4 accP = (f32x4){0.f, 0.f, 0.f, 0.f};
            f32x4 accQ = (f32x4){0.f, 0.f, 0.f, 0.f};
            accP = __builtin_amdgcn_mfma_f32_16x16x32_bf16(ah0, bh0, accP, 0, 0, 0);
            accQ = __builtin_amdgcn_mfma_f32_16x16x32_bf16(ah1, bh1, accQ, 0, 0, 0);
            accP = __builtin_amdgcn_mfma_f32_16x16x32_bf16(al0, bh0, accP, 0, 0, 0);
            accQ = __builtin_amdgcn_mfma_f32_16x16x32_bf16(al1, bh1, accQ, 0, 0, 0);

#pragma unroll
            for (int rg = 0; rg < 4; ++rg) {
                float t16 = fmaf(m2k16, accQ[rg],
                                 fmaf(m2k16, accP[rg], ki[rg] + kj16[nf]));
                float e4 = EXP2F(t16);       // exp2(t/16)
                float e3 = e4 * e4;          // squaring chain
                float e2 = e3 * e3;
                float e1 = e2 * e2;
                float e0 = e1 * e1;
                float es = ((e0 + e1) + (e2 + e3)) + e4;
                if (diag) {
                    int i = mf * 16 + (int)rquad + rg;
                    int j = nf * 16 + (int)lrow;
                    float w = (j > i) ? 2.f : ((j == i) ? 1.f : 0.f);
                    es *= w;
                }
                if (rg & 1) eacc1 += es; else eacc0 += es;
            }
        }
    }

    double acc_d = (double)((eacc0 + eacc1) * (diag ? wsign : 2.f * wsign));
#pragma unroll
    for (int o = 32; o > 0; o >>= 1) acc_d += __shfl_down(acc_d, o);
    if (lane == 0) pblock[wg] = acc_d;
}

// Final reduce: block b sums its batch's 2080 wave-tile partials.
__global__ __launch_bounds__(256) void finalize_kernel(const double* __restrict__ pblock,
                                                       float* __restrict__ out) {
    int b = blockIdx.x, t = threadIdx.x;
    const double* p = pblock + (size_t)b * TRI_PER_BATCH;
    double s = 0.0;
    for (int i = t; i < TRI_PER_BATCH; i += 256) s += p[i];
#pragma unroll
    for (int o = 32; o > 0; o >>= 1) s += __shfl_down(s, o);
    __shared__ double w[4];
    if ((t & 63) == 0) w[t >> 6] = s;
    __syncthreads();
    if (t == 0)
        out[b] = (float)((w[0] + w[1] + w[2] + w[3]) / ((double)N_HALF * (double)N_HALF));
}

extern "C" void kernel_launch(void* const* d_in, const int* in_sizes, int n_in,
                              void* d_out, int out_size, void* d_ws, size_t ws_size,
                              hipStream_t stream) {
    const float* x = (const float*)d_in[0];
    const float* y = (const float*)d_in[1];
    float* out = (float*)d_out;
    char* ws = (char*)d_ws;

    // pblock aliases the colsum_part region: colsum dead after bw_kernel,
    // pblock written by mmd strictly later in the same stream.
    float*  k0arr       = (float*)ws;                     // [0, 16)
    float*  ssq_part    = (float*)(ws + 4096);            // 1 KB
    float*  colsum_part = (float*)(ws + 8192);            // 64 KB (dies at bw)
    double* pblock      = (double*)(ws + 8192);           // 8320*8 = 66560 B
    float*  sq          = (float*)(ws + 77824);           // 64 KB
    unsigned short* tot_hi = (unsigned short*)(ws + 143360);            // 2 MB
    unsigned short* tot_lo = (unsigned short*)(ws + 143360 + 2097152);  // 2 MB

    prep_kernel<<<256, 256, 0, stream>>>(x, y, tot_hi, tot_lo, sq, ssq_part, colsum_part);
    bw_kernel<<<BATCH, 256, 0, stream>>>(ssq_part, colsum_part, k0arr);
    mmd_mfma<<<NWG, 64, 0, stream>>>(tot_hi, tot_lo, sq, k0arr, pblock);
    finalize_kernel<<<BATCH, 256, 0, stream>>>(pblock, out);
}

// Round 14
// 43.691 us; speedup vs baseline: 1.4699x; 1.0045x over previous
//
#include <hip/hip_runtime.h>

#define N_TOT 4096
#define N_HALF 2048
#define DIMS 64
#define BATCH 4
#define WGRID 64              // 4096/64 wave-tile rows
#define TRI_PER_BATCH 2080    // 64*65/2 upper-tri 64x64 wave-tiles
#define NWG (BATCH * TRI_PER_BATCH)   // 8320, divisible by 8

typedef __attribute__((ext_vector_type(8))) short short8;
typedef __attribute__((ext_vector_type(4))) float f32x4;

#if __has_builtin(__builtin_amdgcn_exp2f)
#define EXP2F(x) __builtin_amdgcn_exp2f(x)
#else
#define EXP2F(x) exp2f(x)
#endif

__device__ __forceinline__ unsigned short f2bf_rne(float f) {
    unsigned int u = __float_as_uint(f);
    unsigned int r = (u + 0x7FFFu + ((u >> 16) & 1u)) >> 16;
    return (unsigned short)r;
}
__device__ __forceinline__ float bf2f(unsigned short h) {
    return __uint_as_float(((unsigned int)h) << 16);
}

// Prep: fp32 -> bf16 hi/lo split, row sq-norms, per-block partials for Ssq and
// colsum. 256 blocks x 256 thr x 16 floats.
__global__ __launch_bounds__(256) void prep_kernel(const float* __restrict__ x,
                                                   const float* __restrict__ y,
                                                   unsigned short* __restrict__ hi,
                                                   unsigned short* __restrict__ lo,
                                                   float* __restrict__ sq,
                                                   float* __restrict__ ssq_part,
                                                   float* __restrict__ colsum_part) {
    int g = blockIdx.x;
    int t = threadIdx.x;
    bool isx = g < 128;
    int gg = isx ? g : g - 128;
    int base = gg << 12;
    int b = gg >> 5;
    const float* src = isx ? x : y;

    float q_acc = 0.f;
    float4 c_acc = {0.f, 0.f, 0.f, 0.f};
#pragma unroll
    for (int it = 0; it < 4; ++it) {
        int e = base + (it << 10) + (t << 2);
        int rem = e & 131071;
        float4 v = *(const float4*)(src + e);
        unsigned dst = (unsigned)b * 262144u + (isx ? 0u : 131072u) + (unsigned)rem;
        ushort4 h, l;
        h.x = f2bf_rne(v.x); l.x = f2bf_rne(v.x - bf2f(h.x));
        h.y = f2bf_rne(v.y); l.y = f2bf_rne(v.y - bf2f(h.y));
        h.z = f2bf_rne(v.z); l.z = f2bf_rne(v.z - bf2f(h.z));
        h.w = f2bf_rne(v.w); l.w = f2bf_rne(v.w - bf2f(h.w));
        *(ushort4*)(hi + dst) = h;
        *(ushort4*)(lo + dst) = l;

        float p = fmaf(v.x, v.x, fmaf(v.y, v.y, fmaf(v.z, v.z, v.w * v.w)));
        p += __shfl_xor(p, 1);
        p += __shfl_xor(p, 2);
        p += __shfl_xor(p, 4);
        p += __shfl_xor(p, 8);
        int rwi = rem >> 6;
        if ((t & 15) == 0)
            sq[b * N_TOT + (isx ? rwi : N_HALF + rwi)] = p;

        float q = p;
        q += __shfl_xor(q, 16);
        q += __shfl_xor(q, 32);
        q_acc += q;

        float4 c = v;
        c.x += __shfl_xor(c.x, 16); c.y += __shfl_xor(c.y, 16);
        c.z += __shfl_xor(c.z, 16); c.w += __shfl_xor(c.w, 16);
        c.x += __shfl_xor(c.x, 32); c.y += __shfl_xor(c.y, 32);
        c.z += __shfl_xor(c.z, 32); c.w += __shfl_xor(c.w, 32);
        c_acc.x += c.x; c_acc.y += c.y; c_acc.z += c.z; c_acc.w += c.w;
    }

    __shared__ float wsum[4];
    __shared__ float4 csh[4][16];
    int wid = t >> 6;
    if ((t & 63) == 0) wsum[wid] = q_acc;
    if ((t & 63) < 16) csh[wid][t & 63] = c_acc;
    __syncthreads();
    if (t == 0) ssq_part[g] = wsum[0] + wsum[1] + wsum[2] + wsum[3];
    if (t < 16) {
        float4 s0 = csh[0][t], s1 = csh[1][t], s2 = csh[2][t], s3 = csh[3][t];
        float4 o;
        o.x = s0.x + s1.x + s2.x + s3.x;
        o.y = s0.y + s1.y + s2.y + s3.y;
        o.z = s0.z + s1.z + s2.z + s3.z;
        o.w = s0.w + s1.w + s2.w + s3.w;
        *(float4*)(colsum_part + (size_t)g * 64 + t * 4) = o;
    }
}

// Reduce partials -> k0[b]. 4 blocks (one per batch).
__global__ __launch_bounds__(256) void bw_kernel(const float* __restrict__ ssq_part,
                                                 const float* __restrict__ colsum_part,
                                                 float* __restrict__ k0arr) {
    int b = blockIdx.x;
    int t = threadIdx.x;
    int c = t & 63, q = t >> 6;
    float cs = 0.f;
#pragma unroll
    for (int pp = 0; pp < 16; ++pp) {
        int p = q * 16 + pp;
        int g = (p < 32) ? (b * 32 + p) : (128 + b * 32 + (p - 32));
        cs += colsum_part[(size_t)g * 64 + c];
    }
    __shared__ float csq[4][64];
    csq[q][c] = cs;
    __syncthreads();
    if (t < 64) {
        float col = csq[0][t] + csq[1][t] + csq[2][t] + csq[3][t];
        double cc = (double)col * (double)col;
#pragma unroll
        for (int o = 32; o > 0; o >>= 1) cc += __shfl_xor(cc, o);
        int g = (t < 32) ? (b * 32 + t) : (128 + b * 32 + (t - 32));
        double sd = (double)ssq_part[g];
#pragma unroll
        for (int o = 32; o > 0; o >>= 1) sd += __shfl_xor(sd, o);
        if (t == 0) {
            double sumL2 = 2.0 * (double)N_TOT * sd - 2.0 * cc;
            double bw = sumL2 / ((double)N_TOT * (double)N_TOT - (double)N_TOT);
            bw *= 0.25;
            k0arr[b] = (float)(-1.4426950408889634 / bw);
        }
    }
}

// Main: SINGLE-WAVE blocks (64 threads), 64x64 upper-tri wave-tiles, NO
// barriers anywhere. 2-pass MFMA: dot' = (ah+al)*bh = a*bh exactly -> B-lo
// never needed (MFMA -33%, LDS panel 8 KB, LDS reads halve). B-hi staged
// wave-locally; A hi+lo direct from L2 (consecutive tiles share A rows).
__global__ void mmd_mfma(const unsigned short* __restrict__ hi,
                         const unsigned short* __restrict__ lo,
                         const float* __restrict__ sq,
                         const float* __restrict__ k0arr,
                         double* __restrict__ pblock) {
    // bijective XCD swizzle (NWG % 8 == 0)
    int wg0 = blockIdx.x;
    int wg = (wg0 & 7) * (NWG / 8) + (wg0 >> 3);
    int b = wg / TRI_PER_BATCH;
    int r = wg % TRI_PER_BATCH;
    int ib = 0, cum = 0;
    while (r >= cum + (WGRID - ib)) { cum += WGRID - ib; ++ib; }
    int jb = ib + (r - cum);
    unsigned i0 = (unsigned)ib * 64u;
    unsigned j0 = (unsigned)jb * 64u;
    int lane = threadIdx.x;           // 0..63

    const unsigned short* Hb = hi + (unsigned)b * 262144u;
    const unsigned short* Lb = lo + (unsigned)b * 262144u;
    const float* sqb = sq + b * N_TOT;

    // ---- stage B-hi panel (64 rows x 64 k = 8 KB), [slot8][row64] layout ----
    // shorts index = slot*512 + row*8; slot s holds k-chunk s (8 bf16).
    __shared__ short ldsB[4096];
    {
        unsigned gb = (j0 + (unsigned)lane) * 64u;
#pragma unroll
        for (int k = 0; k < 8; ++k) {
            short8 v = *(const short8*)(Hb + gb + (unsigned)k * 8u);
            *(short8*)(ldsB + k * 512 + lane * 8) = v;
        }
    }
    // no __syncthreads: single wave; compiler orders ds_read after ds_write.

    bool diag = (ib == jb);
    float wsign = ((i0 < (unsigned)N_HALF) == (j0 < (unsigned)N_HALF)) ? 1.f : -1.f;
    float k16 = k0arr[b] * 0.0625f;      // k0/16
    float m2k16 = -2.f * k16;
    unsigned lrow = (unsigned)(lane & 15);
    unsigned grp = (unsigned)(lane >> 4);   // k-chunk group 0..3
    unsigned rquad = grp * 4u;
    unsigned kbase = grp * 8u;

    float kj16[4];
#pragma unroll
    for (int nf = 0; nf < 4; ++nf)
        kj16[nf] = k16 * sqb[j0 + (unsigned)nf * 16u + lrow];

    const short* B0 = ldsB + grp * 512;          // k-half 0 slot base
    float eacc0 = 0.f, eacc1 = 0.f;

#pragma unroll
    for (int mf = 0; mf < 4; ++mf) {
        unsigned ra = (i0 + (unsigned)mf * 16u + lrow) * 64u + kbase;
        short8 ah0 = *(const short8*)(Hb + ra);
        short8 ah1 = *(const short8*)(Hb + ra + 32u);
        short8 al0 = *(const short8*)(Lb + ra);
        short8 al1 = *(const short8*)(Lb + ra + 32u);
        float4 sv = *(const float4*)(sqb + i0 + (unsigned)mf * 16u + rquad);
        float ki[4] = {k16 * sv.x, k16 * sv.y, k16 * sv.z, k16 * sv.w};

#pragma unroll
        for (int nf = 0; nf < 4; ++nf) {
            const short* bp = B0 + (nf * 16 + (int)lrow) * 8;
            short8 bh0 = *(const short8*)(bp);
            short8 bh1 = *(const short8*)(bp + 2048);   // k-half 1 (slot+4)

            // dot = a*bh exactly: (ah + al) x bh via two passes per k-half
            f32x4 accP = (f32x4){0.f, 0.f, 0.f, 0.f};
            f32x4 accQ = (f32x4){0.f, 0.f, 0.f, 0.f};
            accP = __builtin_amdgcn_mfma_f32_16x16x32_bf16(ah0, bh0, accP, 0, 0, 0);
            accQ = __builtin_amdgcn_mfma_f32_16x16x32_bf16(ah1, bh1, accQ, 0, 0, 0);
            accP = __builtin_amdgcn_mfma_f32_16x16x32_bf16(al0, bh0, accP, 0, 0, 0);
            accQ = __builtin_amdgcn_mfma_f32_16x16x32_bf16(al1, bh1, accQ, 0, 0, 0);

#pragma unroll
            for (int rg = 0; rg < 4; ++rg) {
                float t16 = fmaf(m2k16, accQ[rg],
                                 fmaf(m2k16, accP[rg], ki[rg] + kj16[nf]));
                float e4 = EXP2F(t16);       // exp2(t/16)
                float e3 = e4 * e4;          // squaring chain
                float e2 = e3 * e3;
                float e1 = e2 * e2;
                float e0 = e1 * e1;
                float es = ((e0 + e1) + (e2 + e3)) + e4;
                if (diag) {
                    int i = mf * 16 + (int)rquad + rg;
                    int j = nf * 16 + (int)lrow;
                    float w = (j > i) ? 2.f : ((j == i) ? 1.f : 0.f);
                    es *= w;
                }
                if (rg & 1) eacc1 += es; else eacc0 += es;
            }
        }
    }

    double acc_d = (double)((eacc0 + eacc1) * (diag ? wsign : 2.f * wsign));
#pragma unroll
    for (int o = 32; o > 0; o >>= 1) acc_d += __shfl_down(acc_d, o);
    if (lane == 0) pblock[wg] = acc_d;
}

// Final reduce: block b sums its batch's 2080 wave-tile partials.
__global__ __launch_bounds__(256) void finalize_kernel(const double* __restrict__ pblock,
                                                       float* __restrict__ out) {
    int b = blockIdx.x, t = threadIdx.x;
    const double* p = pblock + (size_t)b * TRI_PER_BATCH;
    double s = 0.0;
    for (int i = t; i < TRI_PER_BATCH; i += 256) s += p[i];
#pragma unroll
    for (int o = 32; o > 0; o >>= 1) s += __shfl_down(s, o);
    __shared__ double w[4];
    if ((t & 63) == 0) w[t >> 6] = s;
    __syncthreads();
    if (t == 0)
        out[b] = (float)((w[0] + w[1] + w[2] + w[3]) / ((double)N_HALF * (double)N_HALF));
}

extern "C" void kernel_launch(void* const* d_in, const int* in_sizes, int n_in,
                              void* d_out, int out_size, void* d_ws, size_t ws_size,
                              hipStream_t stream) {
    const float* x = (const float*)d_in[0];
    const float* y = (const float*)d_in[1];
    float* out = (float*)d_out;
    char* ws = (char*)d_ws;

    // pblock aliases the colsum_part region: colsum dead after bw_kernel,
    // pblock written by mmd strictly later in the same stream.
    float*  k0arr       = (float*)ws;                     // [0, 16)
    float*  ssq_part    = (float*)(ws + 4096);            // 1 KB
    float*  colsum_part = (float*)(ws + 8192);            // 64 KB (dies at bw)
    double* pblock      = (double*)(ws + 8192);           // 8320*8 = 66560 B
    float*  sq          = (float*)(ws + 77824);           // 64 KB
    unsigned short* tot_hi = (unsigned short*)(ws + 143360);            // 2 MB
    unsigned short* tot_lo = (unsigned short*)(ws + 143360 + 2097152);  // 2 MB

    prep_kernel<<<256, 256, 0, stream>>>(x, y, tot_hi, tot_lo, sq, ssq_part, colsum_part);
    bw_kernel<<<BATCH, 256, 0, stream>>>(ssq_part, colsum_part, k0arr);
    mmd_mfma<<<NWG, 64, 0, stream>>>(tot_hi, tot_lo, sq, k0arr, pblock);
    finalize_kernel<<<BATCH, 256, 0, stream>>>(pblock, out);
}